// Round 5
// baseline (104.063 us; speedup 1.0000x reference)
//
#include <hip/hip_runtime.h>

#define BATCH 8192
#define V 128
#define H 512
#define NET_W (2 * V)   // 256
#define MAGIC 0x5A5A5A5Au

// Fused persistent kernel: 256 blocks x 512 threads (<=1 block/CU on 256 CUs,
// so all blocks are co-resident -> the device-scope barrier cannot deadlock).
//
// Phase A (block b: row = b>>1, half = b&1):
//   net_half = relu(W1[row,:] + b1) @ W2[:, half*128:...] + b2  (4-way K-split),
//   serial t0 argmax (first-occurrence tie-break = jnp.argmax) -> loc/scale.
//   Publish: agent-scope RELEASE store of flags[b] = MAGIC (orders the
//   loc/scale store before the flag; emits L2 writeback to the coherence pt).
//
// Barrier: thread t<256 spin-ACQUIRES flags[t] (cache-wide inv on gfx950),
//   then __syncthreads(). flags start at harness poison 0xAAAAAAAA != MAGIC,
//   re-armed by the harness's re-poison before every call.
//
// Phase B: 32 batch rows per block (8 waves x 4 iters, one wave per row),
//   float4 I/O, LDS per-wave index broadcast, all indices masked to [0,128).
__global__ __launch_bounds__(512) void fused_flow_kernel(
        const float* __restrict__ inputs,
        const float* __restrict__ W1,
        const float* __restrict__ b1,
        const float* __restrict__ W2,
        const float* __restrict__ b2,
        float* __restrict__ out,
        int* __restrict__ loc_idx,
        int* __restrict__ scale_idx,
        unsigned* __restrict__ flags) {
    __shared__ float h[H];
    __shared__ float part[4][V];
    __shared__ float net[V];
    __shared__ int s_idx0[8];
    __shared__ int s_a[8];

    const int t = threadIdx.x;             // 0..511

    // ---------------- Phase A ----------------
    {
        const int row  = blockIdx.x >> 1;
        const int half = blockIdx.x & 1;
        const int c    = t & (V - 1);      // column within half
        const int k    = t >> 7;           // K-chunk 0..3

        float v = W1[row * H + t] + b1[t];
        h[t] = v > 0.0f ? v : 0.0f;
        __syncthreads();

        const float* __restrict__ w2p = W2 + (size_t)(k * 128) * NET_W + half * V + c;
        const float* __restrict__ hp  = h + k * 128;
        float acc = 0.0f;
#pragma unroll 8
        for (int j = 0; j < 128; ++j) {
            acc = fmaf(hp[j], w2p[(size_t)j * NET_W], acc);
        }
        part[k][c] = acc;
        __syncthreads();

        if (t < V) {
            net[t] = part[0][t] + part[1][t] + part[2][t] + part[3][t]
                   + b2[half * V + t];
        }
        __syncthreads();

        if (t == 0) {
            float best = net[0]; int bi = 0;
            for (int i = 1; i < V; ++i) {
                if (net[i] > best) { best = net[i]; bi = i; }
            }
            if (half == 0) loc_idx[row] = bi;
            else           scale_idx[row] = bi;
            // Release: loc/scale store ordered before the flag at agent scope.
            __hip_atomic_store(&flags[blockIdx.x], MAGIC,
                               __ATOMIC_RELEASE, __HIP_MEMORY_SCOPE_AGENT);
        }
    }

    // ---------------- Device-scope barrier ----------------
    if (t < 256) {
        while (__hip_atomic_load(&flags[t], __ATOMIC_ACQUIRE,
                                 __HIP_MEMORY_SCOPE_AGENT) != MAGIC) {
            __builtin_amdgcn_s_sleep(1);
        }
    }
    __syncthreads();

    // ---------------- Phase B ----------------
    const int wid  = t >> 6;               // wave slot 0..7
    const int lane = t & 63;

    for (int iter = 0; iter < 4; ++iter) {
        const int b = blockIdx.x * 32 + iter * 8 + wid;

        // Lane i holds row elements [4i,4i+4): lanes 0..31 = x0, 32..63 = x1.
        const float4 v = ((const float4*)inputs)[(size_t)b * 64 + lane];

        const int local = (v.x > 0.5f) ? 0 :
                          (v.y > 0.5f) ? 1 :
                          (v.z > 0.5f) ? 2 :
                          (v.w > 0.5f) ? 3 : -1;
        if (local >= 0) {
            const int pos = lane * 4 + local;      // hot column in [0,256)
            if (pos < V) s_idx0[wid] = pos;        // argwhere(x0)
            else         s_a[wid]    = pos - V;    // argwhere(x1)
        }
        __syncthreads();

        const int idx0 = s_idx0[wid] & (V - 1);
        const int a    = s_a[wid]    & (V - 1);
        const int l    = loc_idx[idx0];
        const int s    = scale_idx[idx0];
        const int zc   = (a * s + l) & (V - 1);
        const int hot  = (s != 0) ? (V + zc) : -1;

        float4 o;
        if (lane < 32) {
            o = v;  // copy x0 verbatim
        } else {
            const int c0 = lane * 4;
            o.x = (c0 + 0 == hot) ? 1.0f : 0.0f;
            o.y = (c0 + 1 == hot) ? 1.0f : 0.0f;
            o.z = (c0 + 2 == hot) ? 1.0f : 0.0f;
            o.w = (c0 + 3 == hot) ? 1.0f : 0.0f;
        }
        ((float4*)out)[(size_t)b * 64 + lane] = o;
        __syncthreads();
    }
}

extern "C" void kernel_launch(void* const* d_in, const int* in_sizes, int n_in,
                              void* d_out, int out_size, void* d_ws, size_t ws_size,
                              hipStream_t stream) {
    const float* inputs = (const float*)d_in[0];  // (8192, 256)
    const float* W1     = (const float*)d_in[1];  // (128, 512)
    const float* b1     = (const float*)d_in[2];  // (512,)
    const float* W2     = (const float*)d_in[3];  // (512, 256)
    const float* b2     = (const float*)d_in[4];  // (256,)
    float* out = (float*)d_out;                   // (8192, 256)

    int*      loc_idx   = (int*)d_ws;             // 128 ints
    int*      scale_idx = loc_idx + V;            // 128 ints
    unsigned* flags     = (unsigned*)(scale_idx + V);  // 256 u32 (poison-armed)

    fused_flow_kernel<<<2 * V, 512, 0, stream>>>(
        inputs, W1, b1, W2, b2, out, loc_idx, scale_idx, flags);
}

// Round 6
// 75.541 us; speedup vs baseline: 1.3776x; 1.3776x over previous
//
#include <hip/hip_runtime.h>

#define BATCH 8192
#define V 128
#define H 512
#define NET_W (2 * V)   // 256

// Kernel A: one block per (idx0 row, output half). 256 blocks x 512 threads.
//   half 0 -> net[0:128]  -> loc_idx[row]
//   half 1 -> net[128:256]-> scale_idx[row]
// Parallel GEMM (4-way K-split per column, dual-accumulator ILP), then serial
// thread-0 argmax (first-occurrence tie-break, matches jnp.argmax).
__global__ __launch_bounds__(512) void precompute_argmax_kernel(
        const float* __restrict__ W1,
        const float* __restrict__ b1,
        const float* __restrict__ W2,
        const float* __restrict__ b2,
        int* __restrict__ loc_idx,
        int* __restrict__ scale_idx) {
    __shared__ float h[H];
    __shared__ float part[4][V];
    __shared__ float net[V];

    const int row  = blockIdx.x >> 1;
    const int half = blockIdx.x & 1;
    const int t    = threadIdx.x;          // 0..511
    const int c    = t & (V - 1);          // column within half: 0..127
    const int k    = t >> 7;               // K-chunk: 0..3

    // h[j] = relu(W1[row, j] + b1[j])
    {
        float v = W1[row * H + t] + b1[t];
        h[t] = v > 0.0f ? v : 0.0f;
    }
    __syncthreads();

    // Partial dot over j in [k*128, (k+1)*128), output column = half*128 + c.
    // Two independent 64-FMA chains (ILP) instead of one serial 128 chain.
    const float* __restrict__ w2p = W2 + (size_t)(k * 128) * NET_W + half * V + c;
    const float* __restrict__ hp  = h + k * 128;
    float acc0 = 0.0f, acc1 = 0.0f;
#pragma unroll 8
    for (int j = 0; j < 128; j += 2) {
        acc0 = fmaf(hp[j],     w2p[(size_t)j * NET_W],       acc0);
        acc1 = fmaf(hp[j + 1], w2p[(size_t)(j + 1) * NET_W], acc1);
    }
    part[k][c] = acc0 + acc1;
    __syncthreads();

    if (t < V) {
        net[t] = part[0][t] + part[1][t] + part[2][t] + part[3][t]
               + b2[half * V + t];
    }
    __syncthreads();

    if (t == 0) {
        float best = net[0]; int bi = 0;
        for (int i = 1; i < V; ++i) {
            if (net[i] > best) { best = net[i]; bi = i; }
        }
        if (half == 0) loc_idx[row] = bi;
        else           scale_idx[row] = bi;
    }
}

// Kernel B: one wave per batch row, 4 rows per 256-thread block, float4 I/O.
// Index discovery via LDS broadcast; all data-dependent indices masked to
// [0,128) so no path can read OOB. (Unchanged from R3 — proven.)
__global__ __launch_bounds__(256) void flow_kernel(
        const float* __restrict__ inputs,
        const int* __restrict__ loc_idx,
        const int* __restrict__ scale_idx,
        float* __restrict__ out) {
    __shared__ int s_idx0[4];
    __shared__ int s_a[4];

    const int tid  = threadIdx.x;
    const int wid  = tid >> 6;    // row slot within block: 0..3
    const int lane = tid & 63;
    const int b    = blockIdx.x * 4 + wid;

    // Lane i holds row elements [4i, 4i+4): lanes 0..31 = x0, 32..63 = x1.
    const float4 v = ((const float4*)inputs)[(size_t)b * 64 + lane];

    const int local = (v.x > 0.5f) ? 0 :
                      (v.y > 0.5f) ? 1 :
                      (v.z > 0.5f) ? 2 :
                      (v.w > 0.5f) ? 3 : -1;
    if (local >= 0) {
        const int pos = lane * 4 + local;          // hot column in [0,256)
        if (pos < V) s_idx0[wid] = pos;            // argwhere(x0)
        else         s_a[wid]    = pos - V;        // argwhere(x1)
    }
    __syncthreads();

    const int idx0 = s_idx0[wid] & (V - 1);
    const int a    = s_a[wid]    & (V - 1);
    const int l    = loc_idx[idx0];
    const int s    = scale_idx[idx0];
    const int zc   = (a * s + l) & (V - 1);        // target col within z1
    const int hot  = (s != 0) ? (V + zc) : -1;     // col within full 256-row

    float4 o;
    if (lane < 32) {
        o = v;  // copy x0 verbatim
    } else {
        const int c0 = lane * 4;
        o.x = (c0 + 0 == hot) ? 1.0f : 0.0f;
        o.y = (c0 + 1 == hot) ? 1.0f : 0.0f;
        o.z = (c0 + 2 == hot) ? 1.0f : 0.0f;
        o.w = (c0 + 3 == hot) ? 1.0f : 0.0f;
    }
    ((float4*)out)[(size_t)b * 64 + lane] = o;
}

extern "C" void kernel_launch(void* const* d_in, const int* in_sizes, int n_in,
                              void* d_out, int out_size, void* d_ws, size_t ws_size,
                              hipStream_t stream) {
    const float* inputs = (const float*)d_in[0];  // (8192, 256)
    const float* W1     = (const float*)d_in[1];  // (128, 512)
    const float* b1     = (const float*)d_in[2];  // (512,)
    const float* W2     = (const float*)d_in[3];  // (512, 256)
    const float* b2     = (const float*)d_in[4];  // (256,)
    float* out = (float*)d_out;                   // (8192, 256)

    int* loc_idx   = (int*)d_ws;        // 128 ints
    int* scale_idx = loc_idx + V;       // 128 ints

    precompute_argmax_kernel<<<2 * V, 512, 0, stream>>>(W1, b1, W2, b2, loc_idx, scale_idx);
    flow_kernel<<<BATCH / 4, 256, 0, stream>>>(inputs, loc_idx, scale_idx, out);
}